// Round 19
// baseline (80.271 us; speedup 1.0000x reference)
//
#include <hip/hip_runtime.h>

// Periodogram: out[b,m] = (re^2 + im^2)/N,  re = aC + bS, im = bC - aS
// r19: r16 chassis (barrier-free, wave-private LDS DMA double-buffer,
// 16x16x32 MFMA) re-tiled to fm=2,fn=2 (32x32 per wave) so 4 waves/SIMD
// fit (lb(256,4)) -> 4 independent phase streams feed the matrix pipe.

typedef __fp16 half8  __attribute__((ext_vector_type(8)));
typedef __fp16 half2v __attribute__((ext_vector_type(2)));
typedef float  f32x4  __attribute__((ext_vector_type(4)));

#define B_SZ 512
#define N_SZ 1024
#define M_SZ 16384
#define KT 32
#define NT (N_SZ / KT)
#define WS_ARR 1048576   // bytes per converted array (512*1024*2)

union U4 { half2v h2[4]; uint4 u; };
union BF { half2v h2[4]; half8 v; uint4 u; };

__device__ __forceinline__ void gld16(const void* g, void* l) {
    __builtin_amdgcn_global_load_lds((__attribute__((address_space(1))) void*)g,
                                     (__attribute__((address_space(3))) void*)l,
                                     16, 0, 0);
}

// ---- pre-kernel: x (f32) -> d_ws (f16, fragment-tiled 16-row x 32-k, 1KB) ----
__global__ __launch_bounds__(256)
void cvt_kernel(const float* __restrict__ x, unsigned char* __restrict__ ws) {
    const int id  = (int)blockIdx.x * 256 + (int)threadIdx.x;  // 0..131071
    const int arr = id >> 16;            // 0=a, 1=b
    const int rem = id & 65535;
    const int rb  = rem >> 11;           // row block 0..31
    const int kc  = (rem >> 6) & 31;     // k chunk 0..31
    const int l6  = rem & 63;
    const int r16 = l6 >> 2;             // row in block
    const int g   = l6 & 3;              // k sub-group
    const float* src = x + (size_t)(rb * 16 + r16) * 2048 + arr * 1024 + kc * 32 + g * 8;
    const float4 v0 = *(const float4*)src;
    const float4 v1 = *(const float4*)(src + 4);
    U4 u;
    u.h2[0] = __builtin_amdgcn_cvt_pkrtz(v0.x, v0.y);
    u.h2[1] = __builtin_amdgcn_cvt_pkrtz(v0.z, v0.w);
    u.h2[2] = __builtin_amdgcn_cvt_pkrtz(v1.x, v1.y);
    u.h2[3] = __builtin_amdgcn_cvt_pkrtz(v1.z, v1.w);
    *(uint4*)(ws + (size_t)arr * WS_ARR + (size_t)(rb * 32 + kc) * 1024 + (g * 16 + r16) * 16) = u.u;
}

__global__ __launch_bounds__(256, 4)
void periodogram_kernel(const unsigned char* __restrict__ ws,
                        const float* __restrict__ xgrid,
                        float* __restrict__ out) {
    // 4 waves x 2 buffers x 4 KB (A frags 0..2K, B frags 2K..4K), wave-private
    __shared__ __align__(16) unsigned char smem[32768];
    const int tid  = (int)threadIdx.x;
    const int lane = tid & 63;
    const int w    = tid >> 6;
    const int bid  = (int)blockIdx.x;
    const int b0 = (bid & 7) * 64;        // 8 b-tiles of 64
    const int m0 = (bid >> 3) * 64;       // 256 m-tiles of 64

    const int wr = (w >> 1) * 32;   // wave row offset in tile
    const int wc = (w & 1) * 32;    // wave col offset in tile

    unsigned char* lb = smem + (unsigned)(w * 8192);
    const int l15 = lane & 15;

    // ---- fragment source pointers (lane-linear within 1KB tiles) ----
    const unsigned char* pA[2];
#pragma unroll
    for (int fm = 0; fm < 2; ++fm) {
        const int rb = ((b0 + wr) >> 4) + fm;
        pA[fm] = ws + (size_t)(rb * 32) * 1024 + (size_t)(lane * 16);
    }

    // ---- per-lane trig state for the B operand (register-resident) ----
    half2v PC[2][4], PS[2][4];
    float c0v[2], s0v[2], C32[2], S32[2];
    const float g8f = (float)((lane >> 4) << 3);
#pragma unroll
    for (int fn = 0; fn < 2; ++fn) {
        const float xg = xgrid[m0 + wc + fn * 16 + l15];
        float Cj[8], Sj[8];
        Cj[0] = 1.0f; Sj[0] = 0.0f;
#pragma unroll
        for (int j = 1; j < 8; ++j) {
            float p = xg * (float)j; p -= floorf(p);
            Cj[j] = __builtin_amdgcn_cosf(p);   // cos(2*pi*p)
            Sj[j] = __builtin_amdgcn_sinf(p);
        }
#pragma unroll
        for (int i = 0; i < 4; ++i) {
            PC[fn][i] = __builtin_amdgcn_cvt_pkrtz(Cj[2 * i], Cj[2 * i + 1]);
            PS[fn][i] = __builtin_amdgcn_cvt_pkrtz(Sj[2 * i], Sj[2 * i + 1]);
        }
        float p32 = xg * 32.0f; p32 -= floorf(p32);      // exact product
        C32[fn] = __builtin_amdgcn_cosf(p32);
        S32[fn] = __builtin_amdgcn_sinf(p32);
        float pb = xg * g8f; pb -= floorf(pb);
        c0v[fn] = __builtin_amdgcn_cosf(pb);
        s0v[fn] = __builtin_amdgcn_sinf(pb);
    }

    f32x4 accRe[2][2], accIm[2][2];
#pragma unroll
    for (int i = 0; i < 2; ++i)
#pragma unroll
        for (int j = 0; j < 2; ++j) { accRe[i][j] = (f32x4)0.0f; accIm[i][j] = (f32x4)0.0f; }

    // ---- prologue: DMA-stage t=0 into buffer 0 (wave-private) ----
#pragma unroll
    for (int fm = 0; fm < 2; ++fm) {
        gld16(pA[fm], lb + (unsigned)(fm * 1024));
        gld16(pA[fm] + WS_ARR, lb + (unsigned)(2048 + fm * 1024));
    }

    for (int t = 0; t < NT; ++t) {
        const unsigned cb = (unsigned)(t & 1) * 4096u;
        // current buffer's DMA complete (only this wave's loads are counted)
        asm volatile("s_waitcnt vmcnt(0)" ::: "memory");
        // ---- ds_read fragments (lane-linear, conflict-free b128) ----
        half8 fa[2], fb[2];
#pragma unroll
        for (int fm = 0; fm < 2; ++fm) {
            fa[fm] = *(const half8*)(lb + cb + (unsigned)(fm * 1024) + (unsigned)(lane * 16));
            fb[fm] = *(const half8*)(lb + cb + (unsigned)(2048 + fm * 1024) + (unsigned)(lane * 16));
        }
        // ---- issue next step's DMA into the other buffer ----
        if (t < NT - 1) {
            const unsigned nb = cb ^ 4096u;
            const unsigned off = (unsigned)((t + 1) * 1024);
#pragma unroll
            for (int fm = 0; fm < 2; ++fm) {
                gld16(pA[fm] + off, lb + nb + (unsigned)(fm * 1024));
                gld16(pA[fm] + WS_ARR + off, lb + nb + (unsigned)(2048 + fm * 1024));
            }
        }
        // ---- compute: trig in registers + two-pass MFMA ----
#pragma unroll
        for (int fn = 0; fn < 2; ++fn) {
            const float c0 = c0v[fn], s0 = s0v[fn];
            const half2v c0b = __builtin_amdgcn_cvt_pkrtz(c0, c0);
            const half2v s0b = __builtin_amdgcn_cvt_pkrtz(s0, s0);
            BF fc, fs, fns;
#pragma unroll
            for (int i = 0; i < 4; ++i) {
                fc.h2[i] = c0b * PC[fn][i] - s0b * PS[fn][i];   // pk_mul+pk_fma
                fs.h2[i] = s0b * PC[fn][i] + c0b * PS[fn][i];
            }
            __builtin_amdgcn_s_setprio(1);
            // pass 1: independent first-layer products
#pragma unroll
            for (int fm = 0; fm < 2; ++fm) {
                accRe[fm][fn] = __builtin_amdgcn_mfma_f32_16x16x32_f16(fa[fm], fc.v, accRe[fm][fn], 0, 0, 0);
                accIm[fm][fn] = __builtin_amdgcn_mfma_f32_16x16x32_f16(fb[fm], fc.v, accIm[fm][fn], 0, 0, 0);
            }
            // fns under matrix latency
            fns.u.x = fs.u.x ^ 0x80008000u;
            fns.u.y = fs.u.y ^ 0x80008000u;
            fns.u.z = fs.u.z ^ 0x80008000u;
            fns.u.w = fs.u.w ^ 0x80008000u;
            // pass 2: second layer
#pragma unroll
            for (int fm = 0; fm < 2; ++fm) {
                accRe[fm][fn] = __builtin_amdgcn_mfma_f32_16x16x32_f16(fb[fm], fs.v,  accRe[fm][fn], 0, 0, 0);
                accIm[fm][fn] = __builtin_amdgcn_mfma_f32_16x16x32_f16(fa[fm], fns.v, accIm[fm][fn], 0, 0, 0);
            }
            __builtin_amdgcn_s_setprio(0);
            // advance base state by Delta-k = 32 (f32, depth-2)
            c0v[fn] = __builtin_fmaf(c0, C32[fn], -(s0 * S32[fn]));
            s0v[fn] = __builtin_fmaf(s0, C32[fn],  (c0 * S32[fn]));
        }
    }

    // ---- epilogue: out = (re^2 + im^2)/N ----
    // D frag layout (measured m89): col = lane&15, row = (lane>>4)*4 + reg
    const float inv = 1.0f / (float)N_SZ;
    const int orow0 = b0 + wr + ((lane >> 4) << 2);
    const int ocol0 = m0 + wc + l15;
#pragma unroll
    for (int fm = 0; fm < 2; ++fm)
#pragma unroll
        for (int fn = 0; fn < 2; ++fn) {
            const f32x4 r = accRe[fm][fn];
            const f32x4 im = accIm[fm][fn];
            const int col = ocol0 + fn * 16;
#pragma unroll
            for (int j = 0; j < 4; ++j) {
                const int row = orow0 + fm * 16 + j;
                out[(size_t)row * M_SZ + col] = (r[j] * r[j] + im[j] * im[j]) * inv;
            }
        }
}

extern "C" void kernel_launch(void* const* d_in, const int* in_sizes, int n_in,
                              void* d_out, int out_size, void* d_ws, size_t ws_size,
                              hipStream_t stream) {
    const float* x     = (const float*)d_in[0];
    const float* xgrid = (const float*)d_in[1];
    float* out = (float*)d_out;
    unsigned char* ws = (unsigned char*)d_ws;
    // pre-convert x -> f16 fragment-tiled (2 MB in d_ws)
    cvt_kernel<<<512, 256, 0, stream>>>(x, ws);
    dim3 grid(8 * (M_SZ / 64));   // 8 * 256 = 2048 blocks -> 4 per CU, 2 gens
    dim3 block(256);
    periodogram_kernel<<<grid, block, 0, stream>>>(ws, xgrid, out);
}

// Round 23
// 68.421 us; speedup vs baseline: 1.1732x; 1.1732x over previous
//
#include <hip/hip_runtime.h>

// Periodogram: out[b,m] = (re^2 + im^2)/N,  re = aC + bS, im = bC - aS
// r20: direct-global streaming (r14 chassis, no LDS, no barriers) with
// BT=256 x MT=64 blocks, wave tile fm=8 x fn=2 -> only 2 b-tiles, halving
// the trig-regeneration VALU (trig work ~ M*N*btiles) while keeping the
// MFMA:trig amortization at 16 MFMA per trig build.

typedef __fp16 half8  __attribute__((ext_vector_type(8)));
typedef __fp16 half2v __attribute__((ext_vector_type(2)));
typedef float  f32x4  __attribute__((ext_vector_type(4)));

#define B_SZ 512
#define N_SZ 1024
#define M_SZ 16384
#define KT 32
#define NT (N_SZ / KT)
#define WS_ARR 1048576   // bytes per converted array (512*1024*2)

union U4 { half2v h2[4]; uint4 u; };
union BF { half2v h2[4]; half8 v; uint4 u; };

// ---- pre-kernel: x (f32) -> d_ws (f16, fragment-tiled 16-row x 32-k, 1KB) ----
__global__ __launch_bounds__(256)
void cvt_kernel(const float* __restrict__ x, unsigned char* __restrict__ ws) {
    const int id  = (int)blockIdx.x * 256 + (int)threadIdx.x;  // 0..131071
    const int arr = id >> 16;            // 0=a, 1=b
    const int rem = id & 65535;
    const int rb  = rem >> 11;           // row block 0..31
    const int kc  = (rem >> 6) & 31;     // k chunk 0..31
    const int l6  = rem & 63;
    const int r16 = l6 >> 2;             // row in block
    const int g   = l6 & 3;              // k sub-group
    const float* src = x + (size_t)(rb * 16 + r16) * 2048 + arr * 1024 + kc * 32 + g * 8;
    const float4 v0 = *(const float4*)src;
    const float4 v1 = *(const float4*)(src + 4);
    U4 u;
    u.h2[0] = __builtin_amdgcn_cvt_pkrtz(v0.x, v0.y);
    u.h2[1] = __builtin_amdgcn_cvt_pkrtz(v0.z, v0.w);
    u.h2[2] = __builtin_amdgcn_cvt_pkrtz(v1.x, v1.y);
    u.h2[3] = __builtin_amdgcn_cvt_pkrtz(v1.z, v1.w);
    *(uint4*)(ws + (size_t)arr * WS_ARR + (size_t)(rb * 32 + kc) * 1024 + (g * 16 + r16) * 16) = u.u;
}

__global__ __launch_bounds__(256, 2)
void periodogram_kernel(const unsigned char* __restrict__ ws,
                        const float* __restrict__ xgrid,
                        float* __restrict__ out) {
    const int tid  = (int)threadIdx.x;
    const int lane = tid & 63;
    const int w    = tid >> 6;
    const int bid  = (int)blockIdx.x;
    const int b0 = (bid & 1) * 256;       // 2 b-tiles of 256
    const int m0 = (bid >> 1) * 64;       // 256 m-tiles of 64

    const int wr = (w >> 1) * 128;  // wave row offset in tile (fm=8 -> 128 rows)
    const int wc = (w & 1) * 32;    // wave col offset in tile (fn=2 -> 32 cols)
    const int l15 = lane & 15;

    // ---- fragment source base (lane-linear within 1KB tiles) ----
    const unsigned char* pA0 = ws + (size_t)(((b0 + wr) >> 4) * 32) * 1024 + (size_t)(lane * 16);

    // ---- per-lane trig state for the B operand (register-resident) ----
    half2v PC[2][4], PS[2][4];
    float c0v[2], s0v[2], C32[2], S32[2];
    const float g8f = (float)((lane >> 4) << 3);
#pragma unroll
    for (int fn = 0; fn < 2; ++fn) {
        const float xg = xgrid[m0 + wc + fn * 16 + l15];
        float Cj[8], Sj[8];
        Cj[0] = 1.0f; Sj[0] = 0.0f;
#pragma unroll
        for (int j = 1; j < 8; ++j) {
            float p = xg * (float)j; p -= floorf(p);
            Cj[j] = __builtin_amdgcn_cosf(p);   // cos(2*pi*p)
            Sj[j] = __builtin_amdgcn_sinf(p);
        }
#pragma unroll
        for (int i = 0; i < 4; ++i) {
            PC[fn][i] = __builtin_amdgcn_cvt_pkrtz(Cj[2 * i], Cj[2 * i + 1]);
            PS[fn][i] = __builtin_amdgcn_cvt_pkrtz(Sj[2 * i], Sj[2 * i + 1]);
        }
        float p32 = xg * 32.0f; p32 -= floorf(p32);      // exact product
        C32[fn] = __builtin_amdgcn_cosf(p32);
        S32[fn] = __builtin_amdgcn_sinf(p32);
        float pb = xg * g8f; pb -= floorf(pb);
        c0v[fn] = __builtin_amdgcn_cosf(pb);
        s0v[fn] = __builtin_amdgcn_sinf(pb);
    }

    f32x4 accRe[8][2], accIm[8][2];
#pragma unroll
    for (int i = 0; i < 8; ++i)
#pragma unroll
        for (int j = 0; j < 2; ++j) { accRe[i][j] = (f32x4)0.0f; accIm[i][j] = (f32x4)0.0f; }

    for (int t = 0; t < NT; ++t) {
        // ---- fragment loads: one dwordx4 per (fm, array) from L2 ----
        half8 fa[8], fb[8];
        const unsigned off = (unsigned)(t * 1024);
#pragma unroll
        for (int fm = 0; fm < 8; ++fm) {
            fa[fm] = *(const half8*)(pA0 + (unsigned)(fm * 32768) + off);
            fb[fm] = *(const half8*)(pA0 + WS_ARR + (unsigned)(fm * 32768) + off);
        }
#pragma unroll
        for (int fn = 0; fn < 2; ++fn) {
            const float c0 = c0v[fn], s0 = s0v[fn];
            const half2v c0b = __builtin_amdgcn_cvt_pkrtz(c0, c0);
            const half2v s0b = __builtin_amdgcn_cvt_pkrtz(s0, s0);
            BF fc, fs, fns;
#pragma unroll
            for (int i = 0; i < 4; ++i) {
                fc.h2[i] = c0b * PC[fn][i] - s0b * PS[fn][i];   // pk_mul+pk_fma
                fs.h2[i] = s0b * PC[fn][i] + c0b * PS[fn][i];
            }
            __builtin_amdgcn_s_setprio(1);
            // pass 1: 16 independent first-layer products
#pragma unroll
            for (int fm = 0; fm < 8; ++fm) {
                accRe[fm][fn] = __builtin_amdgcn_mfma_f32_16x16x32_f16(fa[fm], fc.v, accRe[fm][fn], 0, 0, 0);
                accIm[fm][fn] = __builtin_amdgcn_mfma_f32_16x16x32_f16(fb[fm], fc.v, accIm[fm][fn], 0, 0, 0);
            }
            // fns under matrix latency
            fns.u.x = fs.u.x ^ 0x80008000u;
            fns.u.y = fs.u.y ^ 0x80008000u;
            fns.u.z = fs.u.z ^ 0x80008000u;
            fns.u.w = fs.u.w ^ 0x80008000u;
            // pass 2: second layer (RAW distance = 16 MFMAs)
#pragma unroll
            for (int fm = 0; fm < 8; ++fm) {
                accRe[fm][fn] = __builtin_amdgcn_mfma_f32_16x16x32_f16(fb[fm], fs.v,  accRe[fm][fn], 0, 0, 0);
                accIm[fm][fn] = __builtin_amdgcn_mfma_f32_16x16x32_f16(fa[fm], fns.v, accIm[fm][fn], 0, 0, 0);
            }
            __builtin_amdgcn_s_setprio(0);
            // advance base state by Delta-k = 32 (f32, depth-2)
            c0v[fn] = __builtin_fmaf(c0, C32[fn], -(s0 * S32[fn]));
            s0v[fn] = __builtin_fmaf(s0, C32[fn],  (c0 * S32[fn]));
        }
    }

    // ---- epilogue: out = (re^2 + im^2)/N ----
    // D frag layout (measured m89): col = lane&15, row = (lane>>4)*4 + reg
    const float inv = 1.0f / (float)N_SZ;
    const int orow0 = b0 + wr + ((lane >> 4) << 2);
    const int ocol0 = m0 + wc + l15;
#pragma unroll
    for (int fm = 0; fm < 8; ++fm)
#pragma unroll
        for (int fn = 0; fn < 2; ++fn) {
            const f32x4 r = accRe[fm][fn];
            const f32x4 im = accIm[fm][fn];
            const int col = ocol0 + fn * 16;
#pragma unroll
            for (int j = 0; j < 4; ++j) {
                const int row = orow0 + fm * 16 + j;
                out[(size_t)row * M_SZ + col] = (r[j] * r[j] + im[j] * im[j]) * inv;
            }
        }
}

extern "C" void kernel_launch(void* const* d_in, const int* in_sizes, int n_in,
                              void* d_out, int out_size, void* d_ws, size_t ws_size,
                              hipStream_t stream) {
    const float* x     = (const float*)d_in[0];
    const float* xgrid = (const float*)d_in[1];
    float* out = (float*)d_out;
    unsigned char* ws = (unsigned char*)d_ws;
    // pre-convert x -> f16 fragment-tiled (2 MB in d_ws)
    cvt_kernel<<<512, 256, 0, stream>>>(x, ws);
    dim3 grid(2 * (M_SZ / 64));   // 2 * 256 = 512 blocks -> 2 per CU
    dim3 block(256);
    periodogram_kernel<<<grid, block, 0, stream>>>(ws, xgrid, out);
}